// Round 20
// baseline (194.482 us; speedup 1.0000x reference)
//
#include <hip/hip_runtime.h>
#include <cmath>

#define Bdim 8
#define Cdim 768
#define Kdim 256
#define Ndim 4096
#define NT 64       // k1 tokens/block
#define KC2 32      // C-chunk per MFMA iteration
#define NCH (Cdim / KC2)   // 24

typedef __bf16 bf16x8 __attribute__((ext_vector_type(8)));
typedef short  s16x8  __attribute__((ext_vector_type(8)));
typedef float  f32x4  __attribute__((ext_vector_type(4)));
union U8 { s16x8 s; bf16x8 b; };

// direct global->LDS DMA (fallback path only)
typedef __attribute__((address_space(1))) const unsigned int g_u32;
typedef __attribute__((address_space(3))) unsigned int l_u32;
__device__ __forceinline__ void gload16(const void* g, void* l) {
    __builtin_amdgcn_global_load_lds((g_u32*)g, (l_u32*)l, 16, 0, 0);
}

__device__ __forceinline__ unsigned short bf16_rne(float f) {
    unsigned u = __float_as_uint(f);
    unsigned r = u + 0x7FFFu + ((u >> 16) & 1u);
    return (unsigned short)(r >> 16);
}
__device__ __forceinline__ float bf2f(unsigned short h) {
    return __uint_as_float((unsigned)h << 16);
}

// three-level bf16 split, RNE at each level; v = h + m + l + eps, |eps| <= 2^-27 |v|
__device__ __forceinline__ void split3(float v, short& h, short& m, short& l) {
    unsigned u = __float_as_uint(v);
    unsigned th = u + 0x7FFFu + ((u >> 16) & 1u);
    h = (short)(th >> 16);
    float r1 = v - __uint_as_float(th & 0xFFFF0000u);      // exact
    unsigned u1 = __float_as_uint(r1);
    unsigned tm = u1 + 0x7FFFu + ((u1 >> 16) & 1u);
    m = (short)(tm >> 16);
    float r2 = r1 - __uint_as_float(tm & 0xFFFF0000u);     // exact
    unsigned u2 = __float_as_uint(r2);
    unsigned tl = u2 + 0x7FFFu + ((u2 >> 16) & 1u);
    l = (short)(tl >> 16);
}

// Legacy prep (fallback path only).
__global__ __launch_bounds__(256) void prep_kernel(
    const float* __restrict__ cents, float* __restrict__ invc, int* __restrict__ cnt)
{
    __shared__ float red[4][Kdim];
    const int tid = threadIdx.x;
    const int b = blockIdx.x;
    const float* cb = cents + (size_t)b * Cdim * Kdim;
    const int q = tid & 63, g = tid >> 6;
    float4 ss = make_float4(0.f, 0.f, 0.f, 0.f);
    for (int r = g; r < Cdim; r += 4) {
        float4 v = *(const float4*)(cb + (size_t)r * Kdim + q * 4);
        ss.x = fmaf(v.x, v.x, ss.x); ss.y = fmaf(v.y, v.y, ss.y);
        ss.z = fmaf(v.z, v.z, ss.z); ss.w = fmaf(v.w, v.w, ss.w);
    }
    *(float4*)&red[g][q * 4] = ss;
    __syncthreads();
    float s = red[0][tid] + red[1][tid] + red[2][tid] + red[3][tid];
    invc[b * Kdim + tid] = 1.f / fmaxf(sqrtf(s), 1e-12f);
    cnt[b * Kdim + tid] = 0;
}

// Cvt (fallback): centroids -> split-3 planes.
__global__ __launch_bounds__(256) void cvt_kernel(
    const float* __restrict__ cents, short* __restrict__ centH,
    short* __restrict__ centM, short* __restrict__ centL)
{
    const int k = threadIdx.x;
    const int bc = blockIdx.x;
    const float* src = cents + ((size_t)(bc / 96) * Cdim + (size_t)(bc % 96) * 8) * Kdim + k;
    s16x8 H, M, L;
    #pragma unroll
    for (int e = 0; e < 8; ++e) {
        short h, m, l;
        split3(src[(size_t)e * Kdim], h, m, l);
        H[e] = h; M[e] = m; L[e] = l;
    }
    ((s16x8*)centH)[(size_t)bc * 256 + k] = H;
    ((s16x8*)centM)[(size_t)bc * 256 + k] = M;
    ((s16x8*)centL)[(size_t)bc * 256 + k] = L;
}

// Cvt2 (full path): split-3 planes + centroid squared-sum partials.
__global__ __launch_bounds__(256) void cvt2_kernel(
    const float* __restrict__ cents, short* __restrict__ centH,
    short* __restrict__ centM, short* __restrict__ centL,
    float* __restrict__ csq)            // [B*96][256]
{
    const int k = threadIdx.x;
    const int bc = blockIdx.x;          // b*96 + c8
    const float* src = cents + ((size_t)(bc / 96) * Cdim + (size_t)(bc % 96) * 8) * Kdim + k;
    s16x8 H, M, L;
    float sq = 0.f;
    #pragma unroll
    for (int e = 0; e < 8; ++e) {
        float v = src[(size_t)e * Kdim];     // coalesced across lanes (k)
        sq = fmaf(v, v, sq);
        short h, m, l;
        split3(v, h, m, l);
        H[e] = h; M[e] = m; L[e] = l;
    }
    ((s16x8*)centH)[(size_t)bc * 256 + k] = H;
    ((s16x8*)centM)[(size_t)bc * 256 + k] = M;
    ((s16x8*)centL)[(size_t)bc * 256 + k] = L;
    csq[(size_t)bc * 256 + k] = sq;
}

// nrm_reduce: invc = rsqrt(fixed-order 96-partial sum); zero cnt.
__global__ __launch_bounds__(256) void nrm_reduce_kernel(
    const float* __restrict__ csq, float* __restrict__ invc, int* __restrict__ cnt)
{
    const int k = threadIdx.x;
    const int b = blockIdx.x;
    const float* p = csq + (size_t)b * 96 * 256 + k;
    float s0 = 0.f, s1 = 0.f, s2 = 0.f, s3 = 0.f;
    #pragma unroll
    for (int j = 0; j < 96; j += 4) {
        s0 += p[(j + 0) * 256];
        s1 += p[(j + 1) * 256];
        s2 += p[(j + 2) * 256];
        s3 += p[(j + 3) * 256];
    }
    float s = ((s0 + s1) + (s2 + s3));
    invc[b * Kdim + k] = 1.f / fmaxf(sqrtf(s), 1e-12f);
    cnt[b * Kdim + k] = 0;
}

// xpose3: x (B,C,N) f32 -> 3 split planes (B,N,C) bf16 + per-tile norm
// partials xn2p[b][12][N] (deterministic; summed fixed-order in k1).
__global__ __launch_bounds__(256) void xpose3_kernel(
    const float* __restrict__ x,
    unsigned short* __restrict__ xH, unsigned short* __restrict__ xM,
    unsigned short* __restrict__ xL, float* __restrict__ xn2p)
{
    __shared__ float tile[64][68];
    __shared__ float psum[4][64];
    const int tid = threadIdx.x;
    const int bid = blockIdx.x;
    const int b  = bid / (12 * 64);
    const int r  = bid % (12 * 64);
    const int ct = r / 64, nt = r % 64;
    const float* src = x + ((size_t)b * Cdim + ct * 64) * Ndim + nt * 64;
    #pragma unroll
    for (int it = 0; it < 4; ++it) {
        int idx = tid + it * 256;
        int c = idx >> 4, n4 = idx & 15;
        *(float4*)&tile[c][n4 * 4] = *(const float4*)&src[(size_t)c * Ndim + n4 * 4];
    }
    __syncthreads();

    {
        const int grp = tid >> 6, tn = tid & 63;
        float s = 0.f;
        #pragma unroll
        for (int cc = 0; cc < 16; ++cc) {
            float v = tile[grp * 16 + cc][tn];
            s = fmaf(v, v, s);
        }
        psum[grp][tn] = s;
    }
    __syncthreads();
    if (tid < 64)
        xn2p[((size_t)(b * 12 + ct)) * Ndim + nt * 64 + tid] =
            psum[0][tid] + psum[1][tid] + psum[2][tid] + psum[3][tid];

    #pragma unroll
    for (int it = 0; it < 8; ++it) {
        int idx = tid + it * 256;
        int n = idx >> 5, cp = idx & 31;
        short h0, m0, l0, h1, m1, l1;
        split3(tile[cp * 2][n],     h0, m0, l0);
        split3(tile[cp * 2 + 1][n], h1, m1, l1);
        size_t o = ((size_t)(b * Ndim + nt * 64 + n)) * Cdim + ct * 64 + cp * 2;
        *(unsigned*)&xH[o] = (unsigned)(unsigned short)h0 | ((unsigned)(unsigned short)h1 << 16);
        *(unsigned*)&xM[o] = (unsigned)(unsigned short)m0 | ((unsigned)(unsigned short)m1 << 16);
        *(unsigned*)&xL[o] = (unsigned)(unsigned short)l0 | ((unsigned)(unsigned short)l1 << 16);
    }
}

// Fallback transpose (r13): x -> single bf16 plane.
__global__ __launch_bounds__(256) void xpose_kernel(
    const float* __restrict__ x, unsigned short* __restrict__ xTh)
{
    __shared__ float tile[64][68];
    const int tid = threadIdx.x;
    const int bid = blockIdx.x;
    const int b  = bid / (12 * 64);
    const int r  = bid % (12 * 64);
    const int ct = r / 64, nt = r % 64;
    const float* src = x + ((size_t)b * Cdim + ct * 64) * Ndim + nt * 64;
    #pragma unroll
    for (int it = 0; it < 4; ++it) {
        int idx = tid + it * 256;
        int c = idx >> 4, n4 = idx & 15;
        *(float4*)&tile[c][n4 * 4] = *(const float4*)&src[(size_t)c * Ndim + n4 * 4];
    }
    __syncthreads();
    #pragma unroll
    for (int it = 0; it < 8; ++it) {
        int idx = tid + it * 256;
        int n = idx >> 5, cp = idx & 31;
        unsigned pk = (unsigned)bf16_rne(tile[cp * 2][n])
                    | ((unsigned)bf16_rne(tile[cp * 2 + 1][n]) << 16);
        *(unsigned*)&xTh[((size_t)(b * Ndim + nt * 64 + n)) * Cdim + ct * 64 + cp * 2] = pk;
    }
}

// Scan: per batch — exclusive prefix over cnt, then bucket token ids.
__global__ __launch_bounds__(256) void scan_kernel(
    const int* __restrict__ cnt, const int* __restrict__ kArr,
    int* __restrict__ bucketOff, int* __restrict__ toks)
{
    __shared__ int cS[256];
    __shared__ int offS[256];
    __shared__ int cur[256];
    const int tid = threadIdx.x;
    const int b = blockIdx.x;
    cS[tid] = cnt[b * 256 + tid];
    __syncthreads();
    if (tid == 0) {
        int a = 0;
        for (int k = 0; k < 256; ++k) { offS[k] = a; a += cS[k]; }
    }
    __syncthreads();
    bucketOff[b * 256 + tid] = offS[tid];
    cur[tid] = offS[tid];
    __syncthreads();
    for (int i = tid; i < Ndim; i += 256) {
        int k = kArr[b * Ndim + i];
        int pos = atomicAdd(&cur[k], 1);
        toks[b * Ndim + pos] = i;
    }
}

// AggB: per (b, 2 k-buckets): register-gather aggregation, fused epilogue.
__global__ __launch_bounds__(192) void aggB_kernel(
    const unsigned short* __restrict__ xTh,
    const float* __restrict__ cents,
    const float* __restrict__ wArr,
    const int* __restrict__ toks,
    const int* __restrict__ bucketOff,
    const int* __restrict__ cnt,
    float* __restrict__ hyp)
{
    const int tid = threadIdx.x;
    const int b  = blockIdx.x >> 7;
    const int kg = blockIdx.x & 127;
    const int t4 = tid * 4;
    #pragma unroll
    for (int j = 0; j < 2; ++j) {
        const int k = kg * 2 + j;
        const int off = bucketOff[b * 256 + k];
        const int num = cnt[b * 256 + k];
        const int base = b * Ndim + off;
        float a0 = 0.f, a1 = 0.f, a2 = 0.f, a3 = 0.f;
        int i = 0;
        for (; i + 4 <= num; i += 4) {
            int na = toks[base + i],     nb = toks[base + i + 1];
            int nc = toks[base + i + 2], nd = toks[base + i + 3];
            float wa = wArr[b * Ndim + na], wb = wArr[b * Ndim + nb];
            float wc = wArr[b * Ndim + nc], wd = wArr[b * Ndim + nd];
            ushort4 ha = *(const ushort4*)&xTh[((size_t)(b * Ndim + na)) * Cdim + t4];
            ushort4 hb = *(const ushort4*)&xTh[((size_t)(b * Ndim + nb)) * Cdim + t4];
            ushort4 hc = *(const ushort4*)&xTh[((size_t)(b * Ndim + nc)) * Cdim + t4];
            ushort4 hd = *(const ushort4*)&xTh[((size_t)(b * Ndim + nd)) * Cdim + t4];
            a0 += wa * bf2f(ha.x) + wb * bf2f(hb.x) + wc * bf2f(hc.x) + wd * bf2f(hd.x);
            a1 += wa * bf2f(ha.y) + wb * bf2f(hb.y) + wc * bf2f(hc.y) + wd * bf2f(hd.y);
            a2 += wa * bf2f(ha.z) + wb * bf2f(hb.z) + wc * bf2f(hc.z) + wd * bf2f(hd.z);
            a3 += wa * bf2f(ha.w) + wb * bf2f(hb.w) + wc * bf2f(hc.w) + wd * bf2f(hd.w);
        }
        for (; i < num; ++i) {
            int n = toks[base + i];
            float w = wArr[b * Ndim + n];
            ushort4 h = *(const ushort4*)&xTh[((size_t)(b * Ndim + n)) * Cdim + t4];
            a0 += w * bf2f(h.x); a1 += w * bf2f(h.y);
            a2 += w * bf2f(h.z); a3 += w * bf2f(h.w);
        }
        float d = (float)(num + 1);
        float4 o;
        o.x = (a0 + cents[((size_t)b * Cdim + t4 + 0) * Kdim + k]) / d;
        o.y = (a1 + cents[((size_t)b * Cdim + t4 + 1) * Kdim + k]) / d;
        o.z = (a2 + cents[((size_t)b * Cdim + t4 + 2) * Kdim + k]) / d;
        o.w = (a3 + cents[((size_t)b * Cdim + t4 + 3) * Kdim + k]) / d;
        *(float4*)&hyp[((size_t)(b * Kdim + k)) * Cdim + t4] = o;
    }
}

#define PASS(Afr, Bfr)                                                        \
    _Pragma("unroll")                                                         \
    for (int kf = 0; kf < 4; ++kf)                                            \
        _Pragma("unroll")                                                     \
        for (int nf = 0; nf < 4; ++nf)                                        \
            acc[kf][nf] = __builtin_amdgcn_mfma_f32_16x16x32_bf16(            \
                Afr[kf].b, Bfr[nf].b, acc[kf][nf], 0, 0, 0);

// K1 (full path, r20): BARRIER-FREE register-dataflow MFMA.  No LDS in the
// main loop, no __syncthreads, no manual vmcnt — ordering is pure register
// dependences.  Per chunk: [A(t) 12 loads | B(t+1) 12 loads into named
// even/odd dbuf | 96 MFMA].  A issues FIRST so the compiler's wait on A
// (FIFO vmcnt) does NOT drain the younger B prefetch -> B gets a full
// chunk (~2000 cyc) of slack; A pays only its ~200cyc L2 latency.
// Waves free-run (different phases) -> setprio(1) around MFMA pays (T5).
// Cost: 4x redundant B loads across waves (L2 absorbs, ~21 TB/s < ceiling).
__global__ __launch_bounds__(256, 2) void sim_reg_kernel(
    const short* __restrict__ xH, const short* __restrict__ xM,
    const short* __restrict__ xL,
    const short* __restrict__ centH, const short* __restrict__ centM,
    const short* __restrict__ centL,
    const float* __restrict__ alpha_p, const float* __restrict__ beta_p,
    const float* __restrict__ invc, const float* __restrict__ xn2p,
    float* __restrict__ simOut, float* __restrict__ wArr,
    int* __restrict__ kArr, int* __restrict__ cnt)
{
    __shared__ float bwv[4][NT];
    __shared__ int   bwk[4][NT];

    const int tid  = threadIdx.x;
    const int lane = tid & 63;
    const int w    = tid >> 6;          // wave: k-range [w*64, w*64+64)
    const int q    = lane >> 4;
    const int c15  = lane & 15;
    const int b    = blockIdx.x & 7;            // batch<->XCD affinity
    const int n0   = (blockIdx.x >> 3) * NT;

    // B fragment bases (16B units): record (n, rec) at (b*N+n)*96 + rec
    const s16x8* xHp = (const s16x8*)xH;
    const s16x8* xMp = (const s16x8*)xM;
    const s16x8* xLp = (const s16x8*)xL;
    size_t rB[4];
    #pragma unroll
    for (int nf = 0; nf < 4; ++nf)
        rB[nf] = ((size_t)b * Ndim + n0 + nf * 16 + c15) * 96 + q;

    const s16x8* cHb = (const s16x8*)centH + (size_t)b * 96 * 256;
    const s16x8* cMb = (const s16x8*)centM + (size_t)b * 96 * 256;
    const s16x8* cLb = (const s16x8*)centL + (size_t)b * 96 * 256;
    const int rowA0 = w * 64 + c15;

    #define LOADB(BH, BM, BL, t_) do {                                        \
        _Pragma("unroll")                                                     \
        for (int nf = 0; nf < 4; ++nf) BH[nf].s = xHp[rB[nf] + (t_) * 4];     \
        _Pragma("unroll")                                                     \
        for (int nf = 0; nf < 4; ++nf) BM[nf].s = xMp[rB[nf] + (t_) * 4];     \
        _Pragma("unroll")                                                     \
        for (int nf = 0; nf < 4; ++nf) BL[nf].s = xLp[rB[nf] + (t_) * 4];     \
    } while (0)

    f32x4 acc[4][4];
    #pragma unroll
    for (int i = 0; i < 4; ++i)
        #pragma unroll
        for (int j = 0; j < 4; ++j) acc[i][j] = (f32x4){0.f, 0.f, 0.f, 0.f};

    U8 bH0[4], bM0[4], bL0[4];          // B for even chunks
    U8 bH1[4], bM1[4], bL1[4];          // B for odd chunks

    LOADB(bH0, bM0, bL0, 0);            // prologue: B(0)

    #define CHUNK(t_, BHc, BMc, BLc, BHn, BMn, BLn)                           \
    {                                                                         \
        __builtin_amdgcn_sched_barrier(0);                                    \
        U8 aH[4], aM[4], aL[4];                                               \
        {   const int ra_ = ((t_) * 4 + q) * 256 + rowA0;                     \
            _Pragma("unroll")                                                 \
            for (int kf = 0; kf < 4; ++kf) {                                  \
                aH[kf].s = cHb[ra_ + kf * 16];                                \
                aM[kf].s = cMb[ra_ + kf * 16];                                \
                aL[kf].s = cLb[ra_ + kf * 16];                                \
            }                                                                 \
        }                                                                     \
        __builtin_amdgcn_sched_barrier(0);                                    \
        { const int tn_ = ((t_) + 1 < NCH) ? (t_) + 1 : NCH - 1;              \
          LOADB(BHn, BMn, BLn, tn_); }                                        \
        __builtin_amdgcn_sched_barrier(0);                                    \
        __builtin_amdgcn_s_setprio(1);                                        \
        PASS(aH, BHc) PASS(aM, BHc) PASS(aL, BHc)                             \
        PASS(aH, BMc) PASS(aM, BMc) PASS(aH, BLc)                             \
        __builtin_amdgcn_s_setprio(0);                                        \
    }

    for (int t = 0; t < NCH; t += 2) {
        CHUNK(t,     bH0, bM0, bL0, bH1, bM1, bL1);   // even: use B0, pre B1
        CHUNK(t + 1, bH1, bM1, bL1, bH0, bM0, bL0);   // odd:  use B1, pre B0
    }
    #undef CHUNK
    #undef LOADB

    const float alpha = alpha_p[0];
    const float beta  = beta_p[0];

    // epilogue: deterministic norm (fixed-order 12-partial sum), sigmoid,
    // first-win argmax.  D layout: row(k_local)=q*4+reg, col(n)=c15.
    #pragma unroll
    for (int nf = 0; nf < 4; ++nf) {
        const int n = n0 + nf * 16 + c15;
        float xs = 0.f;
        #pragma unroll
        for (int j = 0; j < 12; ++j) xs += xn2p[(size_t)(b * 12 + j) * Ndim + n];
        const float ivx = 1.f / fmaxf(sqrtf(xs), 1e-12f);
        float best = -1.f; int bk = 0;
        #pragma unroll
        for (int kf = 0; kf < 4; ++kf) {
            float4 ic = *(const float4*)&invc[b * Kdim + w * 64 + kf * 16 + q * 4];
            #pragma unroll
            for (int r = 0; r < 4; ++r) {
                float cosv = acc[kf][nf][r] * ((const float*)&ic)[r] * ivx;
                float s = 1.f / (1.f + expf(-(beta + alpha * cosv)));
                int k = w * 64 + kf * 16 + q * 4 + r;
                if (s > best) { best = s; bk = k; }   // ascending k scan
            }
        }
        #pragma unroll
        for (int off = 16; off < 64; off <<= 1) {
            float ov = __shfl_xor(best, off);
            int   ok = __shfl_xor(bk, off);
            if (ov > best || (ov == best && ok < bk)) { best = ov; bk = ok; }
        }
        if (q == 0) { bwv[w][nf * 16 + c15] = best; bwk[w][nf * 16 + c15] = bk; }
    }
    __syncthreads();
    if (tid < NT) {
        float best = -1.f; int bk = 0;
        #pragma unroll
        for (int g = 0; g < 4; ++g) {    // ascending waves = ascending k
            float v = bwv[g][tid];
            if (v > best) { best = v; bk = bwk[g][tid]; }
        }
        int gn = b * Ndim + n0 + tid;
        wArr[gn] = best;
        kArr[gn] = bk;
        simOut[((size_t)(b * Kdim + bk)) * Ndim + n0 + tid] = best;
        atomicAdd(&cnt[b * Kdim + bk], 1);
    }
}

// K1 (fallback, r13 verbatim): LDS-staged fp32, in-kernel split.
__global__ __launch_bounds__(256, 2) void sim_mfma_kernel(
    const float* __restrict__ x,
    const short* __restrict__ centH,
    const short* __restrict__ centM,
    const short* __restrict__ centL,
    const float* __restrict__ alpha_p,
    const float* __restrict__ beta_p,
    const float* __restrict__ invc,
    float* __restrict__ simOut,
    float* __restrict__ wArr,
    int*   __restrict__ kArr,
    int*   __restrict__ cnt)
{
    __shared__ __align__(16) float sxf[3][KC2][NT];
    __shared__ float invcS[Kdim];
    __shared__ float px[4][NT];
    __shared__ float invxS[NT];
    __shared__ float bwv[4][NT];
    __shared__ int   bwk[4][NT];

    const int tid  = threadIdx.x;
    const int lane = tid & 63;
    const int w    = tid >> 6;
    const int q    = lane >> 4;
    const int c15  = lane & 15;
    const int b    = blockIdx.x >> 6;
    const int n0   = (blockIdx.x & 63) * NT;
    const float* xb = x + (size_t)b * Cdim * Ndim;

    invcS[tid] = invc[b * Kdim + tid];
    const float alpha = alpha_p[0];
    const float beta  = beta_p[0];

    f32x4 acc[4][4];
    #pragma unroll
    for (int i = 0; i < 4; ++i)
        #pragma unroll
        for (int j = 0; j < 4; ++j) acc[i][j] = (f32x4){0.f, 0.f, 0.f, 0.f};

    float xn2p_ = 0.f;

    #define STAGE(t_) do {                                                    \
        const int bf_ = (t_) % 3; const int c0_ = (t_) * KC2;                 \
        _Pragma("unroll")                                                     \
        for (int i_ = 0; i_ < 2; ++i_)                                        \
            gload16(xb + (size_t)(c0_ + w * 8 + i_ * 4 + q) * Ndim            \
                       + n0 + c15 * 4,                                        \
                    &sxf[bf_][w * 8 + i_ * 4][0]);                            \
    } while (0)

    STAGE(0);
    STAGE(1);

    const s16x8* cHb = (const s16x8*)centH + ((size_t)b * 96) * 256;
    const s16x8* cMb = (const s16x8*)centM + ((size_t)b * 96) * 256;
    const s16x8* cLb = (const s16x8*)centL + ((size_t)b * 96) * 256;

    for (int t = 0; t < NCH; ++t) {
        asm volatile("s_waitcnt vmcnt(2)" ::: "memory");
        __builtin_amdgcn_s_barrier();
        __builtin_amdgcn_sched_barrier(0);

        const int cur = t % 3;

        U8 aH[4], aM[4], aL[4];
        {
            const size_t rowb = ((size_t)(t * 4 + q)) * 256 + w * 64 + c15;
            #pragma unroll
            for (int kf = 0; kf < 4; ++kf) {
                aH[kf].s = cHb[rowb + kf * 16];
                aM[kf].s = cMb[rowb + kf * 16];
                aL[kf].s = cLb[rowb + kf * 16];
            }
        }
        if (t + 2 < NCH) STAGE(t + 2);

        #pragma unroll
        for (int r = 0; r < 8; ++r) {
            float v = sxf[cur][w * 8 + r][lane];
            xn2p_ = fmaf(v, v, xn2p_);
        }

        U8 bH[4], bM[4], bL[4];
        #pragma unroll
        for (int nf = 0; nf < 4; ++nf) {
            #pragma unroll
            for (int e = 0; e < 8; ++e) {
                short h, m, l;
                split3(sxf[cur][q * 8 + e][nf * 16 + c15], h, m, l);
                bH[nf].s[e] = h; bM[nf].s[e] = m; bL[nf].s[e] = l;
            }
        }

        PASS(aH, bH) PASS(aH, bM) PASS(aM, bH)
        PASS(aH, bL) PASS(aL, bH) PASS(aM, bM)
    }
    #undef STAGE

    __syncthreads();
    px[w][lane] = xn2p_;
    __syncthreads();
    if (tid < NT) {
        float s = px[0][tid] + px[1][tid] + px[2][tid] + px[3][tid];
        invxS[tid] = 1.f / fmaxf(sqrtf(s), 1e-12f);
    }
    __syncthreads();

    #pragma unroll
    for (int nf = 0; nf < 4; ++nf) {
        const float ivx = invxS[nf * 16 + c15];
        float best = -1.f; int bk = 0;
        #pragma unroll
        for (int kf = 0; kf < 4; ++kf) {
            float4 ic = *(const float4*)&invcS[w * 64 + kf * 16 + q * 4];
            #pragma unroll
            for (int r = 0; r < 4; ++r) {
                float cosv = acc[kf][nf][r] * ((const float*)&ic)[r] * ivx;
                float s = 1.f / (1.f + expf(-(beta + alpha * cosv)));
                int k = w * 64 + kf * 16 + q * 4 + r;
                if (s > best) { best = s; bk = k; }
            }
        }
        #pragma unroll
        for (int off = 16; off < 64; off <<= 1) {
            float ov = __shfl_xor(best, off);
            int   ok = __shfl_xor(bk, off);
            if (ov > best || (ov == best && ok < bk)) { best = ov; bk = ok; }
        }
        if (q == 0) { bwv[w][nf * 16 + c15] = best; bwk[w][nf * 16 + c15] = bk; }
    }
    __syncthreads();
    if (tid < NT) {
        float best = -1.f; int bk = 0;
        #pragma unroll
        for (int g = 0; g < 4; ++g) {
            float v = bwv[g][tid];
            if (v > best) { best = v; bk = bwk[g][tid]; }
        }
        int gn = b * Ndim + n0 + tid;
        wArr[gn] = best;
        kArr[gn] = bk;
        simOut[((size_t)(b * Kdim + bk)) * Ndim + n0 + tid] = best;
        atomicAdd(&cnt[b * Kdim + bk], 1);
    }
}

extern "C" void kernel_launch(void* const* d_in, const int* in_sizes, int n_in,
                              void* d_out, int out_size, void* d_ws, size_t ws_size,
                              hipStream_t stream)
{
    const float* x     = (const float*)d_in[0];
    const float* cents = (const float*)d_in[1];
    const float* alpha = (const float*)d_in[2];
    const float* beta  = (const float*)d_in[3];

    float* hyp    = (float*)d_out;                                    // (B,K,C)
    float* simOut = (float*)d_out + (size_t)Bdim * Kdim * Cdim;       // (B,K,N)

    char* ws = (char*)d_ws;
    hipMemsetAsync(simOut, 0, (size_t)Bdim * Kdim * Ndim * sizeof(float), stream);

    const size_t WS_FULL = 163209216ull;
    const size_t WS_R13  = 60186624ull;

    if (ws_size >= WS_FULL) {
        float* wArr  = (float*)(ws);                            // 131072
        int*   kArr  = (int*)  (ws + 131072);                   // 131072
        int*   cnt   = (int*)  (ws + 262144);                   // 8192
        float* invc  = (float*)(ws + 270336);                   // 8192
        float* xn2p  = (float*)(ws + 278528);                   // 1572864
        short* centH = (short*)(ws + 1851392);                  // 3145728
        short* centM = (short*)(ws + 4997120);                  // 3145728
        short* centL = (short*)(ws + 8142848);                  // 3145728
        int*   toks  = (int*)  (ws + 11288576);                 // 131072
        int*   boff  = (int*)  (ws + 11419648);                 // 8192
        unsigned short* xH = (unsigned short*)(ws + 11427840);  // 50331648
        unsigned short* xM = (unsigned short*)(ws + 61759488);  // 50331648
        unsigned short* xL = (unsigned short*)(ws + 112091136); // 50331648
        float* csq   = (float*)(ws + 162422784);                // 786432

        cvt2_kernel<<<dim3(Bdim * 96), dim3(256), 0, stream>>>(
            cents, centH, centM, centL, csq);
        nrm_reduce_kernel<<<dim3(Bdim), dim3(256), 0, stream>>>(csq, invc, cnt);
        xpose3_kernel<<<dim3(Bdim * 12 * 64), dim3(256), 0, stream>>>(x, xH, xM, xL, xn2p);
        sim_reg_kernel<<<dim3(Bdim * (Ndim / NT)), dim3(256), 0, stream>>>(
            (const short*)xH, (const short*)xM, (const short*)xL,
            centH, centM, centL, alpha, beta, invc, xn2p,
            simOut, wArr, kArr, cnt);
        scan_kernel<<<dim3(Bdim), dim3(256), 0, stream>>>(cnt, kArr, boff, toks);
        aggB_kernel<<<dim3(Bdim * 128), dim3(192), 0, stream>>>(
            xH, cents, wArr, toks, boff, cnt, hyp);
    } else if (ws_size >= WS_R13) {
        float* wArr  = (float*)(ws);
        int*   kArr  = (int*)  (ws + 131072);
        int*   cnt   = (int*)  (ws + 262144);
        float* invc  = (float*)(ws + 270336);
        short* centH = (short*)(ws + 278528);
        short* centM = (short*)(ws + 3424256);
        short* centL = (short*)(ws + 6569984);
        int*   toks  = (int*)  (ws + 9715712);
        int*   boff  = (int*)  (ws + 9846784);
        unsigned short* xTh = (unsigned short*)(ws + 9854976);

        prep_kernel<<<dim3(Bdim), dim3(256), 0, stream>>>(cents, invc, cnt);
        cvt_kernel<<<dim3(Bdim * 96), dim3(256), 0, stream>>>(cents, centH, centM, centL);
        xpose_kernel<<<dim3(Bdim * 12 * 64), dim3(256), 0, stream>>>(x, xTh);
        sim_mfma_kernel<<<dim3(Bdim * (Ndim / NT)), dim3(256), 0, stream>>>(
            x, centH, centM, centL, alpha, beta, invc, simOut, wArr, kArr, cnt);
        scan_kernel<<<dim3(Bdim), dim3(256), 0, stream>>>(cnt, kArr, boff, toks);
        aggB_kernel<<<dim3(Bdim * 128), dim3(192), 0, stream>>>(
            xTh, cents, wArr, toks, boff, cnt, hyp);
    }
}

// Round 21
// 170.157 us; speedup vs baseline: 1.1430x; 1.1430x over previous
//
#include <hip/hip_runtime.h>
#include <cmath>

#define Bdim 8
#define Cdim 768
#define Kdim 256
#define Ndim 4096
#define NT 64       // k1 tokens/block
#define KC2 32      // C-chunk per MFMA iteration
#define NCH (Cdim / KC2)   // 24

typedef __bf16 bf16x8 __attribute__((ext_vector_type(8)));
typedef short  s16x8  __attribute__((ext_vector_type(8)));
typedef float  f32x4  __attribute__((ext_vector_type(4)));
union U8 { s16x8 s; bf16x8 b; };

// direct global->LDS DMA, 16B per lane, wave-uniform LDS base, per-lane src
typedef __attribute__((address_space(1))) const unsigned int g_u32;
typedef __attribute__((address_space(3))) unsigned int l_u32;
__device__ __forceinline__ void gload16(const void* g, void* l) {
    __builtin_amdgcn_global_load_lds((g_u32*)g, (l_u32*)l, 16, 0, 0);
}

__device__ __forceinline__ unsigned short bf16_rne(float f) {
    unsigned u = __float_as_uint(f);
    unsigned r = u + 0x7FFFu + ((u >> 16) & 1u);
    return (unsigned short)(r >> 16);
}
__device__ __forceinline__ float bf2f(unsigned short h) {
    return __uint_as_float((unsigned)h << 16);
}

// three-level bf16 split, RNE at each level; v = h + m + l + eps, |eps| <= 2^-27 |v|
__device__ __forceinline__ void split3(float v, short& h, short& m, short& l) {
    unsigned u = __float_as_uint(v);
    unsigned th = u + 0x7FFFu + ((u >> 16) & 1u);
    h = (short)(th >> 16);
    float r1 = v - __uint_as_float(th & 0xFFFF0000u);      // exact
    unsigned u1 = __float_as_uint(r1);
    unsigned tm = u1 + 0x7FFFu + ((u1 >> 16) & 1u);
    m = (short)(tm >> 16);
    float r2 = r1 - __uint_as_float(tm & 0xFFFF0000u);     // exact
    unsigned u2 = __float_as_uint(r2);
    unsigned tl = u2 + 0x7FFFu + ((u2 >> 16) & 1u);
    l = (short)(tl >> 16);
}

// Legacy prep (fallback path only).
__global__ __launch_bounds__(256) void prep_kernel(
    const float* __restrict__ cents, float* __restrict__ invc, int* __restrict__ cnt)
{
    __shared__ float red[4][Kdim];
    const int tid = threadIdx.x;
    const int b = blockIdx.x;
    const float* cb = cents + (size_t)b * Cdim * Kdim;
    const int q = tid & 63, g = tid >> 6;
    float4 ss = make_float4(0.f, 0.f, 0.f, 0.f);
    for (int r = g; r < Cdim; r += 4) {
        float4 v = *(const float4*)(cb + (size_t)r * Kdim + q * 4);
        ss.x = fmaf(v.x, v.x, ss.x); ss.y = fmaf(v.y, v.y, ss.y);
        ss.z = fmaf(v.z, v.z, ss.z); ss.w = fmaf(v.w, v.w, ss.w);
    }
    *(float4*)&red[g][q * 4] = ss;
    __syncthreads();
    float s = red[0][tid] + red[1][tid] + red[2][tid] + red[3][tid];
    invc[b * Kdim + tid] = 1.f / fmaxf(sqrtf(s), 1e-12f);
    cnt[b * Kdim + tid] = 0;
}

// Cvt (fallback): centroids -> split-3 planes.
__global__ __launch_bounds__(256) void cvt_kernel(
    const float* __restrict__ cents, short* __restrict__ centH,
    short* __restrict__ centM, short* __restrict__ centL)
{
    const int k = threadIdx.x;
    const int bc = blockIdx.x;
    const float* src = cents + ((size_t)(bc / 96) * Cdim + (size_t)(bc % 96) * 8) * Kdim + k;
    s16x8 H, M, L;
    #pragma unroll
    for (int e = 0; e < 8; ++e) {
        short h, m, l;
        split3(src[(size_t)e * Kdim], h, m, l);
        H[e] = h; M[e] = m; L[e] = l;
    }
    ((s16x8*)centH)[(size_t)bc * 256 + k] = H;
    ((s16x8*)centM)[(size_t)bc * 256 + k] = M;
    ((s16x8*)centL)[(size_t)bc * 256 + k] = L;
}

// Cvt2 (full path): split-3 planes + centroid squared-sum partials.
__global__ __launch_bounds__(256) void cvt2_kernel(
    const float* __restrict__ cents, short* __restrict__ centH,
    short* __restrict__ centM, short* __restrict__ centL,
    float* __restrict__ csq)            // [B*96][256]
{
    const int k = threadIdx.x;
    const int bc = blockIdx.x;          // b*96 + c8
    const float* src = cents + ((size_t)(bc / 96) * Cdim + (size_t)(bc % 96) * 8) * Kdim + k;
    s16x8 H, M, L;
    float sq = 0.f;
    #pragma unroll
    for (int e = 0; e < 8; ++e) {
        float v = src[(size_t)e * Kdim];     // coalesced across lanes (k)
        sq = fmaf(v, v, sq);
        short h, m, l;
        split3(v, h, m, l);
        H[e] = h; M[e] = m; L[e] = l;
    }
    ((s16x8*)centH)[(size_t)bc * 256 + k] = H;
    ((s16x8*)centM)[(size_t)bc * 256 + k] = M;
    ((s16x8*)centL)[(size_t)bc * 256 + k] = L;
    csq[(size_t)bc * 256 + k] = sq;
}

// nrm_reduce: invc = rsqrt(fixed-order 96-partial sum); zero cnt.
__global__ __launch_bounds__(256) void nrm_reduce_kernel(
    const float* __restrict__ csq, float* __restrict__ invc, int* __restrict__ cnt)
{
    const int k = threadIdx.x;
    const int b = blockIdx.x;
    const float* p = csq + (size_t)b * 96 * 256 + k;
    float s0 = 0.f, s1 = 0.f, s2 = 0.f, s3 = 0.f;
    #pragma unroll
    for (int j = 0; j < 96; j += 4) {
        s0 += p[(j + 0) * 256];
        s1 += p[(j + 1) * 256];
        s2 += p[(j + 2) * 256];
        s3 += p[(j + 3) * 256];
    }
    float s = ((s0 + s1) + (s2 + s3));
    invc[b * Kdim + k] = 1.f / fmaxf(sqrtf(s), 1e-12f);
    cnt[b * Kdim + k] = 0;
}

// xpose3: x (B,C,N) f32 -> 3 split planes (B,N,C) bf16 + per-tile norm
// partials xn2p[b][12][N] (deterministic; summed fixed-order in k1).
__global__ __launch_bounds__(256) void xpose3_kernel(
    const float* __restrict__ x,
    unsigned short* __restrict__ xH, unsigned short* __restrict__ xM,
    unsigned short* __restrict__ xL, float* __restrict__ xn2p)
{
    __shared__ float tile[64][68];
    __shared__ float psum[4][64];
    const int tid = threadIdx.x;
    const int bid = blockIdx.x;
    const int b  = bid / (12 * 64);
    const int r  = bid % (12 * 64);
    const int ct = r / 64, nt = r % 64;
    const float* src = x + ((size_t)b * Cdim + ct * 64) * Ndim + nt * 64;
    #pragma unroll
    for (int it = 0; it < 4; ++it) {
        int idx = tid + it * 256;
        int c = idx >> 4, n4 = idx & 15;
        *(float4*)&tile[c][n4 * 4] = *(const float4*)&src[(size_t)c * Ndim + n4 * 4];
    }
    __syncthreads();

    {
        const int grp = tid >> 6, tn = tid & 63;
        float s = 0.f;
        #pragma unroll
        for (int cc = 0; cc < 16; ++cc) {
            float v = tile[grp * 16 + cc][tn];
            s = fmaf(v, v, s);
        }
        psum[grp][tn] = s;
    }
    __syncthreads();
    if (tid < 64)
        xn2p[((size_t)(b * 12 + ct)) * Ndim + nt * 64 + tid] =
            psum[0][tid] + psum[1][tid] + psum[2][tid] + psum[3][tid];

    #pragma unroll
    for (int it = 0; it < 8; ++it) {
        int idx = tid + it * 256;
        int n = idx >> 5, cp = idx & 31;
        short h0, m0, l0, h1, m1, l1;
        split3(tile[cp * 2][n],     h0, m0, l0);
        split3(tile[cp * 2 + 1][n], h1, m1, l1);
        size_t o = ((size_t)(b * Ndim + nt * 64 + n)) * Cdim + ct * 64 + cp * 2;
        *(unsigned*)&xH[o] = (unsigned)(unsigned short)h0 | ((unsigned)(unsigned short)h1 << 16);
        *(unsigned*)&xM[o] = (unsigned)(unsigned short)m0 | ((unsigned)(unsigned short)m1 << 16);
        *(unsigned*)&xL[o] = (unsigned)(unsigned short)l0 | ((unsigned)(unsigned short)l1 << 16);
    }
}

// Fallback transpose (r13): x -> single bf16 plane.
__global__ __launch_bounds__(256) void xpose_kernel(
    const float* __restrict__ x, unsigned short* __restrict__ xTh)
{
    __shared__ float tile[64][68];
    const int tid = threadIdx.x;
    const int bid = blockIdx.x;
    const int b  = bid / (12 * 64);
    const int r  = bid % (12 * 64);
    const int ct = r / 64, nt = r % 64;
    const float* src = x + ((size_t)b * Cdim + ct * 64) * Ndim + nt * 64;
    #pragma unroll
    for (int it = 0; it < 4; ++it) {
        int idx = tid + it * 256;
        int c = idx >> 4, n4 = idx & 15;
        *(float4*)&tile[c][n4 * 4] = *(const float4*)&src[(size_t)c * Ndim + n4 * 4];
    }
    __syncthreads();
    #pragma unroll
    for (int it = 0; it < 8; ++it) {
        int idx = tid + it * 256;
        int n = idx >> 5, cp = idx & 31;
        unsigned pk = (unsigned)bf16_rne(tile[cp * 2][n])
                    | ((unsigned)bf16_rne(tile[cp * 2 + 1][n]) << 16);
        *(unsigned*)&xTh[((size_t)(b * Ndim + nt * 64 + n)) * Cdim + ct * 64 + cp * 2] = pk;
    }
}

// Scan: per batch — exclusive prefix over cnt, then bucket token ids.
__global__ __launch_bounds__(256) void scan_kernel(
    const int* __restrict__ cnt, const int* __restrict__ kArr,
    int* __restrict__ bucketOff, int* __restrict__ toks)
{
    __shared__ int cS[256];
    __shared__ int offS[256];
    __shared__ int cur[256];
    const int tid = threadIdx.x;
    const int b = blockIdx.x;
    cS[tid] = cnt[b * 256 + tid];
    __syncthreads();
    if (tid == 0) {
        int a = 0;
        for (int k = 0; k < 256; ++k) { offS[k] = a; a += cS[k]; }
    }
    __syncthreads();
    bucketOff[b * 256 + tid] = offS[tid];
    cur[tid] = offS[tid];
    __syncthreads();
    for (int i = tid; i < Ndim; i += 256) {
        int k = kArr[b * Ndim + i];
        int pos = atomicAdd(&cur[k], 1);
        toks[b * Ndim + pos] = i;
    }
}

// AggB: per (b, 2 k-buckets): register-gather aggregation, fused epilogue.
__global__ __launch_bounds__(192) void aggB_kernel(
    const unsigned short* __restrict__ xTh,
    const float* __restrict__ cents,
    const float* __restrict__ wArr,
    const int* __restrict__ toks,
    const int* __restrict__ bucketOff,
    const int* __restrict__ cnt,
    float* __restrict__ hyp)
{
    const int tid = threadIdx.x;
    const int b  = blockIdx.x >> 7;
    const int kg = blockIdx.x & 127;
    const int t4 = tid * 4;
    #pragma unroll
    for (int j = 0; j < 2; ++j) {
        const int k = kg * 2 + j;
        const int off = bucketOff[b * 256 + k];
        const int num = cnt[b * 256 + k];
        const int base = b * Ndim + off;
        float a0 = 0.f, a1 = 0.f, a2 = 0.f, a3 = 0.f;
        int i = 0;
        for (; i + 4 <= num; i += 4) {
            int na = toks[base + i],     nb = toks[base + i + 1];
            int nc = toks[base + i + 2], nd = toks[base + i + 3];
            float wa = wArr[b * Ndim + na], wb = wArr[b * Ndim + nb];
            float wc = wArr[b * Ndim + nc], wd = wArr[b * Ndim + nd];
            ushort4 ha = *(const ushort4*)&xTh[((size_t)(b * Ndim + na)) * Cdim + t4];
            ushort4 hb = *(const ushort4*)&xTh[((size_t)(b * Ndim + nb)) * Cdim + t4];
            ushort4 hc = *(const ushort4*)&xTh[((size_t)(b * Ndim + nc)) * Cdim + t4];
            ushort4 hd = *(const ushort4*)&xTh[((size_t)(b * Ndim + nd)) * Cdim + t4];
            a0 += wa * bf2f(ha.x) + wb * bf2f(hb.x) + wc * bf2f(hc.x) + wd * bf2f(hd.x);
            a1 += wa * bf2f(ha.y) + wb * bf2f(hb.y) + wc * bf2f(hc.y) + wd * bf2f(hd.y);
            a2 += wa * bf2f(ha.z) + wb * bf2f(hb.z) + wc * bf2f(hc.z) + wd * bf2f(hd.z);
            a3 += wa * bf2f(ha.w) + wb * bf2f(hb.w) + wc * bf2f(hc.w) + wd * bf2f(hd.w);
        }
        for (; i < num; ++i) {
            int n = toks[base + i];
            float w = wArr[b * Ndim + n];
            ushort4 h = *(const ushort4*)&xTh[((size_t)(b * Ndim + n)) * Cdim + t4];
            a0 += w * bf2f(h.x); a1 += w * bf2f(h.y);
            a2 += w * bf2f(h.z); a3 += w * bf2f(h.w);
        }
        float d = (float)(num + 1);
        float4 o;
        o.x = (a0 + cents[((size_t)b * Cdim + t4 + 0) * Kdim + k]) / d;
        o.y = (a1 + cents[((size_t)b * Cdim + t4 + 1) * Kdim + k]) / d;
        o.z = (a2 + cents[((size_t)b * Cdim + t4 + 2) * Kdim + k]) / d;
        o.w = (a3 + cents[((size_t)b * Cdim + t4 + 3) * Kdim + k]) / d;
        *(float4*)&hyp[((size_t)(b * Kdim + k)) * Cdim + t4] = o;
    }
}

#define PASS(Afr, Bfr)                                                        \
    _Pragma("unroll")                                                         \
    for (int kf = 0; kf < 4; ++kf)                                            \
        _Pragma("unroll")                                                     \
        for (int nf = 0; nf < 4; ++nf)                                        \
            acc[kf][nf] = __builtin_amdgcn_mfma_f32_16x16x32_bf16(            \
                Afr[kf].b, Bfr[nf].b, acc[kf][nf], 0, 0, 0);

// K1 (full path, best-measured r18 config): NT=64, LDS-staged pre-split B
// planes (record-slot XOR-swizzle, both-sides), counted vmcnt(3) 3-deep
// pipeline, A-fragment register double-buffer issued at chunk top.
__global__ __launch_bounds__(256, 2) void sim_stage_kernel(
    const short* __restrict__ xH, const short* __restrict__ xM,
    const short* __restrict__ xL,
    const short* __restrict__ centH, const short* __restrict__ centM,
    const short* __restrict__ centL,
    const float* __restrict__ alpha_p, const float* __restrict__ beta_p,
    const float* __restrict__ invc, const float* __restrict__ xn2p,
    float* __restrict__ simOut, float* __restrict__ wArr,
    int* __restrict__ kArr, int* __restrict__ cnt)
{
    __shared__ __align__(16) s16x8 sB[3][3][256];   // 36 KB
    __shared__ float bwv[4][NT];
    __shared__ int   bwk[4][NT];

    const int tid  = threadIdx.x;
    const int lane = tid & 63;
    const int w    = tid >> 6;          // wave: k-range [w*64, w*64+64)
    const int q    = lane >> 4;
    const int c15  = lane & 15;
    const int b    = blockIdx.x & 7;            // batch<->XCD affinity
    const int n0   = (blockIdx.x >> 3) * NT;

    const int nloc = w * 16 + (lane >> 2);
    const int rsw  = (lane & 3) ^ ((nloc >> 1) & 3);
    const size_t gsrc = ((size_t)b * Ndim + n0 + nloc) * 96 + rsw;
    const s16x8* xHp = (const s16x8*)xH;
    const s16x8* xMp = (const s16x8*)xM;
    const s16x8* xLp = (const s16x8*)xL;

    #define STAGE(t_) do { const int bf_ = (t_) % 3;                          \
        gload16(xHp + gsrc + (size_t)(t_) * 4, &sB[bf_][0][w * 64]);          \
        gload16(xMp + gsrc + (size_t)(t_) * 4, &sB[bf_][1][w * 64]);          \
        gload16(xLp + gsrc + (size_t)(t_) * 4, &sB[bf_][2][w * 64]);          \
    } while (0)

    const s16x8* cHb = (const s16x8*)centH + (size_t)b * 96 * 256;
    const s16x8* cMb = (const s16x8*)centM + (size_t)b * 96 * 256;
    const s16x8* cLb = (const s16x8*)centL + (size_t)b * 96 * 256;
    const int rowA0 = w * 64 + c15;

    #define LOADA(dstH, dstM, dstL, t_) do {                                  \
        const int ra_ = ((t_) * 4 + q) * 256 + rowA0;                         \
        _Pragma("unroll")                                                     \
        for (int kf = 0; kf < 4; ++kf) {                                      \
            dstH[kf].s = cHb[ra_ + kf * 16];                                  \
            dstM[kf].s = cMb[ra_ + kf * 16];                                  \
            dstL[kf].s = cLb[ra_ + kf * 16];                                  \
        }                                                                     \
    } while (0)

    f32x4 acc[4][4];
    #pragma unroll
    for (int i = 0; i < 4; ++i)
        #pragma unroll
        for (int j = 0; j < 4; ++j) acc[i][j] = (f32x4){0.f, 0.f, 0.f, 0.f};

    U8 aH0[4], aM0[4], aL0[4];          // A for even chunks
    U8 aH1[4], aM1[4], aL1[4];          // A for odd chunks

    LOADA(aH0, aM0, aL0, 0);            // prologue: A(0)
    STAGE(0);
    STAGE(1);

    const int swz = (c15 >> 1) & 3;     // reader-side record swizzle

    #define CHUNK(t_, aHc, aMc, aLc, aHn, aMn, aLn)                           \
    {                                                                         \
        asm volatile("s_waitcnt vmcnt(3)" ::: "memory");                      \
        __builtin_amdgcn_s_barrier();                                         \
        __builtin_amdgcn_sched_barrier(0);                                    \
        { const int tn_ = ((t_) + 1 < NCH) ? (t_) + 1 : NCH - 1;              \
          LOADA(aHn, aMn, aLn, tn_); }                                        \
        __builtin_amdgcn_sched_barrier(0);                                    \
        if ((t_) + 2 < NCH) STAGE((t_) + 2);                                  \
        const int cur_ = (t_) % 3;                                            \
        U8 bH[4], bM[4], bL[4];                                               \
        _Pragma("unroll")                                                     \
        for (int nf = 0; nf < 4; ++nf) {                                      \
            const int ri = (nf * 16 + c15) * 4 + (q ^ swz);                   \
            bH[nf].s = sB[cur_][0][ri];                                       \
            bM[nf].s = sB[cur_][1][ri];                                       \
            bL[nf].s = sB[cur_][2][ri];                                       \
        }                                                                     \
        PASS(aHc, bH) PASS(aMc, bH) PASS(aLc, bH)                             \
        PASS(aHc, bM) PASS(aMc, bM) PASS(aHc, bL)                             \
    }

    for (int t = 0; t < NCH; t += 2) {
        CHUNK(t,     aH0, aM0, aL0, aH1, aM1, aL1);   // even: use A0, pre A1
        CHUNK(t + 1, aH1, aM1, aL1, aH0, aM0, aL0);   // odd:  use A1, pre A0
    }
    #undef CHUNK
    #undef LOADA
    #undef STAGE

    const float alpha = alpha_p[0];
    const float beta  = beta_p[0];

    // epilogue: deterministic norm (fixed-order 12-partial sum), sigmoid,
    // first-win argmax.  D layout: row(k_local)=q*4+reg, col(n)=c15.
    #pragma unroll
    for (int nf = 0; nf < 4; ++nf) {
        const int n = n0 + nf * 16 + c15;
        float xs = 0.f;
        #pragma unroll
        for (int j = 0; j < 12; ++j) xs += xn2p[(size_t)(b * 12 + j) * Ndim + n];
        const float ivx = 1.f / fmaxf(sqrtf(xs), 1e-12f);
        float best = -1.f; int bk = 0;
        #pragma unroll
        for (int kf = 0; kf < 4; ++kf) {
            float4 ic = *(const float4*)&invc[b * Kdim + w * 64 + kf * 16 + q * 4];
            #pragma unroll
            for (int r = 0; r < 4; ++r) {
                float cosv = acc[kf][nf][r] * ((const float*)&ic)[r] * ivx;
                float s = 1.f / (1.f + expf(-(beta + alpha * cosv)));
                int k = w * 64 + kf * 16 + q * 4 + r;
                if (s > best) { best = s; bk = k; }   // ascending k scan
            }
        }
        #pragma unroll
        for (int off = 16; off < 64; off <<= 1) {
            float ov = __shfl_xor(best, off);
            int   ok = __shfl_xor(bk, off);
            if (ov > best || (ov == best && ok < bk)) { best = ov; bk = ok; }
        }
        if (q == 0) { bwv[w][nf * 16 + c15] = best; bwk[w][nf * 16 + c15] = bk; }
    }
    __syncthreads();
    if (tid < NT) {
        float best = -1.f; int bk = 0;
        #pragma unroll
        for (int g = 0; g < 4; ++g) {    // ascending waves = ascending k
            float v = bwv[g][tid];
            if (v > best) { best = v; bk = bwk[g][tid]; }
        }
        int gn = b * Ndim + n0 + tid;
        wArr[gn] = best;
        kArr[gn] = bk;
        simOut[((size_t)(b * Kdim + bk)) * Ndim + n0 + tid] = best;
        atomicAdd(&cnt[b * Kdim + bk], 1);
    }
}

// K1 (fallback, r13 verbatim): LDS-staged fp32, in-kernel split.
__global__ __launch_bounds__(256, 2) void sim_mfma_kernel(
    const float* __restrict__ x,
    const short* __restrict__ centH,
    const short* __restrict__ centM,
    const short* __restrict__ centL,
    const float* __restrict__ alpha_p,
    const float* __restrict__ beta_p,
    const float* __restrict__ invc,
    float* __restrict__ simOut,
    float* __restrict__ wArr,
    int*   __restrict__ kArr,
    int*   __restrict__ cnt)
{
    __shared__ __align__(16) float sxf[3][KC2][NT];
    __shared__ float invcS[Kdim];
    __shared__ float px[4][NT];
    __shared__ float invxS[NT];
    __shared__ float bwv[4][NT];
    __shared__ int   bwk[4][NT];

    const int tid  = threadIdx.x;
    const int lane = tid & 63;
    const int w    = tid >> 6;
    const int q    = lane >> 4;
    const int c15  = lane & 15;
    const int b    = blockIdx.x >> 6;
    const int n0   = (blockIdx.x & 63) * NT;
    const float* xb = x + (size_t)b * Cdim * Ndim;

    invcS[tid] = invc[b * Kdim + tid];
    const float alpha = alpha_p[0];
    const float beta  = beta_p[0];

    f32x4 acc[4][4];
    #pragma unroll
    for (int i = 0; i < 4; ++i)
        #pragma unroll
        for (int j = 0; j < 4; ++j) acc[i][j] = (f32x4){0.f, 0.f, 0.f, 0.f};

    float xn2p_ = 0.f;

    #define STAGE(t_) do {                                                    \
        const int bf_ = (t_) % 3; const int c0_ = (t_) * KC2;                 \
        _Pragma("unroll")                                                     \
        for (int i_ = 0; i_ < 2; ++i_)                                        \
            gload16(xb + (size_t)(c0_ + w * 8 + i_ * 4 + q) * Ndim            \
                       + n0 + c15 * 4,                                        \
                    &sxf[bf_][w * 8 + i_ * 4][0]);                            \
    } while (0)

    STAGE(0);
    STAGE(1);

    const s16x8* cHb = (const s16x8*)centH + ((size_t)b * 96) * 256;
    const s16x8* cMb = (const s16x8*)centM + ((size_t)b * 96) * 256;
    const s16x8* cLb = (const s16x8*)centL + ((size_t)b * 96) * 256;

    for (int t = 0; t < NCH; ++t) {
        asm volatile("s_waitcnt vmcnt(2)" ::: "memory");
        __builtin_amdgcn_s_barrier();
        __builtin_amdgcn_sched_barrier(0);

        const int cur = t % 3;

        U8 aH[4], aM[4], aL[4];
        {
            const size_t rowb = ((size_t)(t * 4 + q)) * 256 + w * 64 + c15;
            #pragma unroll
            for (int kf = 0; kf < 4; ++kf) {
                aH[kf].s = cHb[rowb + kf * 16];
                aM[kf].s = cMb[rowb + kf * 16];
                aL[kf].s = cLb[rowb + kf * 16];
            }
        }
        if (t + 2 < NCH) STAGE(t + 2);

        #pragma unroll
        for (int r = 0; r < 8; ++r) {
            float v = sxf[cur][w * 8 + r][lane];
            xn2p_ = fmaf(v, v, xn2p_);
        }

        U8 bH[4], bM[4], bL[4];
        #pragma unroll
        for (int nf = 0; nf < 4; ++nf) {
            #pragma unroll
            for (int e = 0; e < 8; ++e) {
                short h, m, l;
                split3(sxf[cur][q * 8 + e][nf * 16 + c15], h, m, l);
                bH[nf].s[e] = h; bM[nf].s[e] = m; bL[nf].s[e] = l;
            }
        }

        PASS(aH, bH) PASS(aH, bM) PASS(aM, bH)
        PASS(aH, bL) PASS(aL, bH) PASS(aM, bM)
    }
    #undef STAGE

    __syncthreads();
    px[w][lane] = xn2p_;
    __syncthreads();
    if (tid < NT) {
        float s = px[0][tid] + px[1][tid] + px[2][tid] + px[3][tid];
        invxS[tid] = 1.f / fmaxf(sqrtf(s), 1e-12f);
    }
    __syncthreads();

    #pragma unroll
    for (int nf = 0; nf < 4; ++nf) {
        const float ivx = invxS[nf * 16 + c15];
        float best = -1.f; int bk = 0;
        #pragma unroll
        for (int kf = 0; kf < 4; ++kf) {
            float4 ic = *(const float4*)&invcS[w * 64 + kf * 16 + q * 4];
            #pragma unroll
            for (int r = 0; r < 4; ++r) {
                float cosv = acc[kf][nf][r] * ((const float*)&ic)[r] * ivx;
                float s = 1.f / (1.f + expf(-(beta + alpha * cosv)));
                int k = w * 64 + kf * 16 + q * 4 + r;
                if (s > best) { best = s; bk = k; }
            }
        }
        #pragma unroll
        for (int off = 16; off < 64; off <<= 1) {
            float ov = __shfl_xor(best, off);
            int   ok = __shfl_xor(bk, off);
            if (ov > best || (ov == best && ok < bk)) { best = ov; bk = ok; }
        }
        if (q == 0) { bwv[w][nf * 16 + c15] = best; bwk[w][nf * 16 + c15] = bk; }
    }
    __syncthreads();
    if (tid < NT) {
        float best = -1.f; int bk = 0;
        #pragma unroll
        for (int g = 0; g < 4; ++g) {
            float v = bwv[g][tid];
            if (v > best) { best = v; bk = bwk[g][tid]; }
        }
        int gn = b * Ndim + n0 + tid;
        wArr[gn] = best;
        kArr[gn] = bk;
        simOut[((size_t)(b * Kdim + bk)) * Ndim + n0 + tid] = best;
        atomicAdd(&cnt[b * Kdim + bk], 1);
    }
}

extern "C" void kernel_launch(void* const* d_in, const int* in_sizes, int n_in,
                              void* d_out, int out_size, void* d_ws, size_t ws_size,
                              hipStream_t stream)
{
    const float* x     = (const float*)d_in[0];
    const float* cents = (const float*)d_in[1];
    const float* alpha = (const float*)d_in[2];
    const float* beta  = (const float*)d_in[3];

    float* hyp    = (float*)d_out;                                    // (B,K,C)
    float* simOut = (float*)d_out + (size_t)Bdim * Kdim * Cdim;       // (B,K,N)

    char* ws = (char*)d_ws;
    hipMemsetAsync(simOut, 0, (size_t)Bdim * Kdim * Ndim * sizeof(float), stream);

    const size_t WS_FULL = 163209216ull;
    const size_t WS_R13  = 60186624ull;

    if (ws_size >= WS_FULL) {
        float* wArr  = (float*)(ws);                            // 131072
        int*   kArr  = (int*)  (ws + 131072);                   // 131072
        int*   cnt   = (int*)  (ws + 262144);                   // 8192
        float* invc  = (float*)(ws + 270336);                   // 8192
        float* xn2p  = (float*)(ws + 278528);                   // 1572864
        short* centH = (short*)(ws + 1851392);                  // 3145728
        short* centM = (short*)(ws + 4997120);                  // 3145728
        short* centL = (short*)(ws + 8142848);                  // 3145728
        int*   toks  = (int*)  (ws + 11288576);                 // 131072
        int*   boff  = (int*)  (ws + 11419648);                 // 8192
        unsigned short* xH = (unsigned short*)(ws + 11427840);  // 50331648
        unsigned short* xM = (unsigned short*)(ws + 61759488);  // 50331648
        unsigned short* xL = (unsigned short*)(ws + 112091136); // 50331648
        float* csq   = (float*)(ws + 162422784);                // 786432

        cvt2_kernel<<<dim3(Bdim * 96), dim3(256), 0, stream>>>(
            cents, centH, centM, centL, csq);
        nrm_reduce_kernel<<<dim3(Bdim), dim3(256), 0, stream>>>(csq, invc, cnt);
        xpose3_kernel<<<dim3(Bdim * 12 * 64), dim3(256), 0, stream>>>(x, xH, xM, xL, xn2p);
        sim_stage_kernel<<<dim3(Bdim * (Ndim / NT)), dim3(256), 0, stream>>>(
            (const short*)xH, (const short*)xM, (const short*)xL,
            centH, centM, centL, alpha, beta, invc, xn2p,
            simOut, wArr, kArr, cnt);
        scan_kernel<<<dim3(Bdim), dim3(256), 0, stream>>>(cnt, kArr, boff, toks);
        aggB_kernel<<<dim3(Bdim * 128), dim3(192), 0, stream>>>(
            xH, cents, wArr, toks, boff, cnt, hyp);
    } else if (ws_size >= WS_R13) {
        float* wArr  = (float*)(ws);
        int*   kArr  = (int*)  (ws + 131072);
        int*   cnt   = (int*)  (ws + 262144);
        float* invc  = (float*)(ws + 270336);
        short* centH = (short*)(ws + 278528);
        short* centM = (short*)(ws + 3424256);
        short* centL = (short*)(ws + 6569984);
        int*   toks  = (int*)  (ws + 9715712);
        int*   boff  = (int*)  (ws + 9846784);
        unsigned short* xTh = (unsigned short*)(ws + 9854976);

        prep_kernel<<<dim3(Bdim), dim3(256), 0, stream>>>(cents, invc, cnt);
        cvt_kernel<<<dim3(Bdim * 96), dim3(256), 0, stream>>>(cents, centH, centM, centL);
        xpose_kernel<<<dim3(Bdim * 12 * 64), dim3(256), 0, stream>>>(x, xTh);
        sim_mfma_kernel<<<dim3(Bdim * (Ndim / NT)), dim3(256), 0, stream>>>(
            x, centH, centM, centL, alpha, beta, invc, simOut, wArr, kArr, cnt);
        scan_kernel<<<dim3(Bdim), dim3(256), 0, stream>>>(cnt, kArr, boff, toks);
        aggB_kernel<<<dim3(Bdim * 128), dim3(192), 0, stream>>>(
            xTh, cents, wArr, toks, boff, cnt, hyp);
    }
}